// Round 2
// baseline (173.491 us; speedup 1.0000x reference)
//
#include <hip/hip_runtime.h>

// Problem constants: B=2, S=2048, D_MODEL=1024, H=16, DK=64.
// Workspace need: ~20.5 MB (og aliases st16; see kernel_launch).

#define LOG2E 1.44269504088896f

using f16   = _Float16;
using f16x4 = __attribute__((ext_vector_type(4))) _Float16;
using f16x8 = __attribute__((ext_vector_type(8))) _Float16;
using f32x4 = __attribute__((ext_vector_type(4))) float;

#define GLDS16(g, l) __builtin_amdgcn_global_load_lds((const __attribute__((address_space(1))) void*)(g), (__attribute__((address_space(3))) void*)(l), 16, 0, 0)
#define GLDS4(g, l)  __builtin_amdgcn_global_load_lds((const __attribute__((address_space(1))) void*)(g), (__attribute__((address_space(3))) void*)(l), 4, 0, 0)

// ---------------------------------------------------------------------------
// K1: blocks 0-1023:   s[b,h,k] = states·Wa  (wave per row) + states->fp16
//     blocks 1024-2047: gsig[b,q,h] = sigmoid(states·Wg + bg)
//     blocks 2048-3071: Wv/Wo -> fp16; cb<512: mask absmax partials
// ---------------------------------------------------------------------------
__global__ __launch_bounds__(256) void k_prep(
    const float* __restrict__ states, const float* __restrict__ mask,
    const float* __restrict__ Wa, const float* __restrict__ Wv,
    const float* __restrict__ Wg, const float* __restrict__ Wo,
    const float* __restrict__ bg,
    f16* __restrict__ st16, f16* __restrict__ Wv16, f16* __restrict__ Wo16,
    float* __restrict__ sbuf, float* __restrict__ gsig, float* __restrict__ partial)
{
  __shared__ float ws[16 * 1024];   // 64 KB
  const int bid = blockIdx.x;
  const int t   = threadIdx.x;
  if (bid < 2048) {
    const bool is_g = bid >= 1024;
    const float* W = is_g ? Wg : Wa;
    for (int i = t; i < 4096; i += 256)
      ((float4*)ws)[i] = ((const float4*)W)[i];
    __syncthreads();
    const int wid = t >> 6, lane = t & 63;
    const int row = (bid & 1023) * 4 + wid;           // 0..4095
    const float* sp = states + (size_t)row * 1024 + lane * 16;
    float x[16];
    #pragma unroll
    for (int j = 0; j < 4; ++j) {
      float4 v = ((const float4*)sp)[j];
      x[j*4+0]=v.x; x[j*4+1]=v.y; x[j*4+2]=v.z; x[j*4+3]=v.w;
    }
    if (!is_g) {
      f16x8 h0, h1;
      #pragma unroll
      for (int j = 0; j < 8; ++j) { h0[j] = (f16)x[j]; h1[j] = (f16)x[8+j]; }
      f16* dp = st16 + (size_t)row * 1024 + lane * 16;
      *(f16x8*)dp = h0; *(f16x8*)(dp + 8) = h1;
    }
    const int b = row >> 11, q = row & 2047;
    for (int h = 0; h < 16; ++h) {
      const float4* wr4 = (const float4*)(ws + h * 1024 + lane * 16);
      float acc = 0.f;
      #pragma unroll
      for (int j = 0; j < 4; ++j) {
        float4 wv4 = wr4[j];
        acc = fmaf(x[j*4+0], wv4.x, acc);
        acc = fmaf(x[j*4+1], wv4.y, acc);
        acc = fmaf(x[j*4+2], wv4.z, acc);
        acc = fmaf(x[j*4+3], wv4.w, acc);
      }
      #pragma unroll
      for (int off = 32; off; off >>= 1) acc += __shfl_xor(acc, off, 64);
      if (lane == 0) {
        if (!is_g) sbuf[(size_t)(b * 16 + h) * 2048 + q] = acc;
        else       gsig[(size_t)row * 16 + h] = 1.f / (1.f + __expf(-(acc + bg[h])));
      }
    }
  } else {
    const int cb = bid - 2048;                         // 0..1023
    { // weight convert: 2 M halves total, 2048 per block
      int idx = cb * 2048 + t * 8;
      const float* src; f16* dst;
      if (idx < 1048576) { src = Wv + idx;             dst = Wv16 + idx; }
      else               { src = Wo + (idx - 1048576); dst = Wo16 + (idx - 1048576); }
      float4 v0 = ((const float4*)src)[0];
      float4 v1 = ((const float4*)src)[1];
      f16x8 h;
      h[0]=(f16)v0.x; h[1]=(f16)v0.y; h[2]=(f16)v0.z; h[3]=(f16)v0.w;
      h[4]=(f16)v1.x; h[5]=(f16)v1.y; h[6]=(f16)v1.z; h[7]=(f16)v1.w;
      *(f16x8*)dst = h;
    }
    if (cb < 512) {
      // mask absmax partial: 512 chunks x 16384 floats = 8,388,608 = B*S*S
      const float4* mp = (const float4*)(mask + (size_t)cb * 16384);
      float mx = 0.f;
      for (int i = 0; i < 16; ++i) {
        float4 v = mp[t + i * 256];
        mx = fmaxf(mx, fmaxf(fmaxf(fabsf(v.x), fabsf(v.y)), fmaxf(fabsf(v.z), fabsf(v.w))));
      }
      #pragma unroll
      for (int off = 32; off; off >>= 1) mx = fmaxf(mx, __shfl_xor(mx, off, 64));
      if ((t & 63) == 0) ws[t >> 6] = mx;
      __syncthreads();
      if (t == 0) partial[cb] = fmaxf(fmaxf(ws[0], ws[1]), fmaxf(ws[2], ws[3]));
    }
  }
}

// ---------------------------------------------------------------------------
// K2: L[b,h] = max_k s[b,h,k] + head_scale[h] * max|mask_b|
// ---------------------------------------------------------------------------
__global__ __launch_bounds__(64) void k_lmax(
    const float* __restrict__ sbuf, const float* __restrict__ partial,
    const float* __restrict__ hs, float* __restrict__ Lbuf)
{
  const int bh = blockIdx.x, l = threadIdx.x;
  float mx = -1e30f;
  for (int i = l; i < 2048; i += 64) mx = fmaxf(mx, sbuf[(size_t)bh * 2048 + i]);
  float mm = 0.f;
  const int b = bh >> 4;
  for (int i = l; i < 256; i += 64) mm = fmaxf(mm, partial[b * 256 + i]);
  #pragma unroll
  for (int off = 32; off; off >>= 1) {
    mx = fmaxf(mx, __shfl_xor(mx, off, 64));
    mm = fmaxf(mm, __shfl_xor(mm, off, 64));
  }
  if (l == 0) Lbuf[bh] = mx + hs[bh & 15] * mm;
}

// ---------------------------------------------------------------------------
// K3: vt[(b*1024 + n)][k] = fp16( states[b,k,:]·Wv[n,:] + bv[n] )   (V stored
// transposed per (b,h): row = b*1024 + h*64 + d, col = k). 128x128 tile,
// BK=32, 4 waves, mfma_f32_16x16x32_f16, global_load_lds w/ XOR swizzle.
// LDS row = 32 halves (64B); slot(16B) = chunk ^ ((row>>1)&3)  -> 2-way max.
// ---------------------------------------------------------------------------
__global__ __launch_bounds__(256) void k_gemm_v(
    const f16* __restrict__ A, const f16* __restrict__ Bw,
    const float* __restrict__ bv, f16* __restrict__ vt)
{
  __shared__ f16 As[4096], Bs[4096];
  const int t = threadIdx.x, wid = t >> 6, lane = t & 63;
  const int r0 = blockIdx.y * 128, n0 = blockIdx.x * 128;
  const int wr = wid >> 1, wc = wid & 1;
  f32x4 acc[4][4] = {};
  const int srow  = t >> 2;
  const int sunit = (t & 3) ^ ((srow >> 1) & 3);
  const f16* ga0 = A  + (size_t)(r0 + srow) * 1024      + sunit * 8;
  const f16* ga1 = A  + (size_t)(r0 + 64 + srow) * 1024 + sunit * 8;
  const f16* gb0 = Bw + (size_t)(n0 + srow) * 1024      + sunit * 8;
  const f16* gb1 = Bw + (size_t)(n0 + 64 + srow) * 1024 + sunit * 8;
  f16* lA0 = As + wid * 512;  f16* lA1 = As + 2048 + wid * 512;
  f16* lB0 = Bs + wid * 512;  f16* lB1 = Bs + 2048 + wid * 512;
  int ra[4], rb[4];
  #pragma unroll
  for (int m = 0; m < 4; ++m) {
    int rr = wr * 64 + m * 16 + (lane & 15);
    ra[m] = rr * 32 + (((lane >> 4) ^ ((rr >> 1) & 3)) * 8);
    rr = wc * 64 + m * 16 + (lane & 15);
    rb[m] = rr * 32 + (((lane >> 4) ^ ((rr >> 1) & 3)) * 8);
  }
  for (int kt = 0; kt < 32; ++kt) {
    const int k0 = kt * 32;
    GLDS16(ga0 + k0, lA0);
    GLDS16(ga1 + k0, lA1);
    GLDS16(gb0 + k0, lB0);
    GLDS16(gb1 + k0, lB1);
    __syncthreads();
    f16x8 a[4], b[4];
    #pragma unroll
    for (int m = 0; m < 4; ++m) a[m] = *(const f16x8*)(As + ra[m]);
    #pragma unroll
    for (int n = 0; n < 4; ++n) b[n] = *(const f16x8*)(Bs + rb[n]);
    #pragma unroll
    for (int m = 0; m < 4; ++m)
      #pragma unroll
      for (int n = 0; n < 4; ++n)
        acc[m][n] = __builtin_amdgcn_mfma_f32_16x16x32_f16(a[m], b[n], acc[m][n], 0, 0, 0);
    __syncthreads();
  }
  const int b_ = r0 >> 11;
  #pragma unroll
  for (int n = 0; n < 4; ++n) {
    const int gn = n0 + wc * 64 + n * 16 + (lane & 15);
    const float bvv = bv[gn];
    #pragma unroll
    for (int m = 0; m < 4; ++m) {
      const int kb = (r0 & 2047) + wr * 64 + m * 16 + ((lane >> 4) << 2);
      f16x4 hv;
      #pragma unroll
      for (int r = 0; r < 4; ++r) hv[r] = (f16)(acc[m][n][r] + bvv);
      *(f16x4*)(vt + (size_t)(b_ * 1024 + gn) * 2048 + kb) = hv;
    }
  }
}

// ---------------------------------------------------------------------------
// K4: fused attention. Block = (h, qtile=64, b), 4 waves. Per k-tile (64):
// stage mask[64q][64k] f32 + vt[64d][64k] f16 + s[64] via global_load_lds
// (source pre-XOR-swizzled); w = exp2((s-L)*log2e + c*log2e*m); P fp16 in
// LDS (wave-local rows); O[16q][64d] += P@V via 8 MFMA. No online rescale:
// L is a precomputed upper bound of the logits. Epilogue: /den * sigmoid(g).
// ---------------------------------------------------------------------------
__global__ __launch_bounds__(256) void k_attn(
    const float* __restrict__ mask, const float* __restrict__ sbuf,
    const float* __restrict__ gsig, const float* __restrict__ hs,
    const float* __restrict__ Lbuf, const f16* __restrict__ vt,
    f16* __restrict__ og)
{
  __shared__ float mk[4096];    // 16 KB, [64q][16 slots of 4 floats] swizzled
  __shared__ f16   vs[4096];    //  8 KB, [64d][8 slots of 8 halves] swizzled
  __shared__ f16   ps[4096];    //  8 KB, [64q][8 slots of 8 halves] swizzled
  __shared__ float st[64];
  __shared__ float den_sh[64];
  const int h = blockIdx.x, qt = blockIdx.y, b = blockIdx.z;
  const int t = threadIdx.x, wid = t >> 6, lane = t & 63;
  const int bh = b * 16 + h;
  const float L  = Lbuf[bh];
  const float c2 = hs[h] * LOG2E;
  const int sq = t >> 2, skc = t & 3;
  const float* mbase = mask + (size_t)b * 2048 * 2048 + (size_t)(qt * 64) * 2048;
  const f16*   vtb   = vt + (size_t)(b * 1024 + h * 64) * 2048;
  const float* sb    = sbuf + (size_t)bh * 2048;
  float denp = 0.f;
  f32x4 acc[4] = {};
  const int mrow_base = t >> 4, mch = t & 15;
  const int vrow = t >> 3, vch = t & 7;

  for (int kt = 0; kt < 32; ++kt) {
    const int k0 = kt * 64;
    #pragma unroll
    for (int i = 0; i < 4; ++i) {
      const int row = i * 16 + mrow_base;
      const int ch  = mch ^ (row & 7);
      GLDS16(mbase + (size_t)row * 2048 + k0 + ch * 4, mk + i * 1024 + wid * 256);
    }
    #pragma unroll
    for (int i = 0; i < 2; ++i) {
      const int d  = i * 32 + vrow;
      const int ch = vch ^ (d & 7);
      GLDS16(vtb + (size_t)d * 2048 + k0 + ch * 8, vs + i * 2048 + wid * 512);
    }
    if (wid == 0) GLDS4(sb + k0 + lane, st);
    __syncthreads();
    // --- softmax phase: this thread owns q-row sq, k-cols skc*16..+15 ---
    f16x8 p0, p1;
    #pragma unroll
    for (int j = 0; j < 4; ++j) {
      f32x4 s4 = *(const f32x4*)(st + skc * 16 + j * 4);
      const int slot = (skc * 4 + j) ^ (sq & 7);
      f32x4 m4 = *(const f32x4*)(mk + sq * 64 + slot * 4);
      #pragma unroll
      for (int e = 0; e < 4; ++e) {
        float w = __builtin_amdgcn_exp2f((s4[e] - L) * LOG2E + c2 * m4[e]);
        denp += w;
        f16 hw = (f16)w;
        if (j < 2) p0[j * 4 + e] = hw; else p1[(j - 2) * 4 + e] = hw;
      }
    }
    {
      const int un0 = (skc * 2)     ^ (sq & 7);
      const int un1 = (skc * 2 + 1) ^ (sq & 7);
      *(f16x8*)(ps + sq * 64 + un0 * 8) = p0;
      *(f16x8*)(ps + sq * 64 + un1 * 8) = p1;
    }
    // --- MFMA phase: P rows of this wave were written by this wave ---
    const int qq = wid * 16 + (lane & 15);
    #pragma unroll
    for (int kk = 0; kk < 2; ++kk) {
      const int ua = (kk * 4 + (lane >> 4)) ^ (qq & 7);
      f16x8 a = *(const f16x8*)(ps + qq * 64 + ua * 8);
      #pragma unroll
      for (int n = 0; n < 4; ++n) {
        const int d  = n * 16 + (lane & 15);
        const int ub = (kk * 4 + (lane >> 4)) ^ (d & 7);
        f16x8 bf = *(const f16x8*)(vs + d * 64 + ub * 8);
        acc[n] = __builtin_amdgcn_mfma_f32_16x16x32_f16(a, bf, acc[n], 0, 0, 0);
      }
    }
    __syncthreads();
  }
  denp += __shfl_xor(denp, 1, 64);
  denp += __shfl_xor(denp, 2, 64);
  if ((lane & 3) == 0) den_sh[wid * 16 + (lane >> 2)] = denp;
  __syncthreads();
  #pragma unroll
  for (int r = 0; r < 4; ++r) {
    const int qloc = ((lane >> 4) << 2) + r;
    const int q = qt * 64 + wid * 16 + qloc;
    const float sc = gsig[(size_t)(b * 2048 + q) * 16 + h] / den_sh[wid * 16 + qloc];
    #pragma unroll
    for (int n = 0; n < 4; ++n)
      og[(size_t)(b * 2048 + q) * 1024 + h * 64 + n * 16 + (lane & 15)] = (f16)(acc[n][r] * sc);
  }
}

// ---------------------------------------------------------------------------
// K5: out[r][n] = og[r,:]·Wo[n,:] + bo[n]  (f32 output)
// ---------------------------------------------------------------------------
__global__ __launch_bounds__(256) void k_gemm_out(
    const f16* __restrict__ A, const f16* __restrict__ Bw,
    const float* __restrict__ bo, float* __restrict__ out)
{
  __shared__ f16 As[4096], Bs[4096];
  const int t = threadIdx.x, wid = t >> 6, lane = t & 63;
  const int r0 = blockIdx.y * 128, n0 = blockIdx.x * 128;
  const int wr = wid >> 1, wc = wid & 1;
  f32x4 acc[4][4] = {};
  const int srow  = t >> 2;
  const int sunit = (t & 3) ^ ((srow >> 1) & 3);
  const f16* ga0 = A  + (size_t)(r0 + srow) * 1024      + sunit * 8;
  const f16* ga1 = A  + (size_t)(r0 + 64 + srow) * 1024 + sunit * 8;
  const f16* gb0 = Bw + (size_t)(n0 + srow) * 1024      + sunit * 8;
  const f16* gb1 = Bw + (size_t)(n0 + 64 + srow) * 1024 + sunit * 8;
  f16* lA0 = As + wid * 512;  f16* lA1 = As + 2048 + wid * 512;
  f16* lB0 = Bs + wid * 512;  f16* lB1 = Bs + 2048 + wid * 512;
  int ra[4], rb[4];
  #pragma unroll
  for (int m = 0; m < 4; ++m) {
    int rr = wr * 64 + m * 16 + (lane & 15);
    ra[m] = rr * 32 + (((lane >> 4) ^ ((rr >> 1) & 3)) * 8);
    rr = wc * 64 + m * 16 + (lane & 15);
    rb[m] = rr * 32 + (((lane >> 4) ^ ((rr >> 1) & 3)) * 8);
  }
  for (int kt = 0; kt < 32; ++kt) {
    const int k0 = kt * 32;
    GLDS16(ga0 + k0, lA0);
    GLDS16(ga1 + k0, lA1);
    GLDS16(gb0 + k0, lB0);
    GLDS16(gb1 + k0, lB1);
    __syncthreads();
    f16x8 a[4], b[4];
    #pragma unroll
    for (int m = 0; m < 4; ++m) a[m] = *(const f16x8*)(As + ra[m]);
    #pragma unroll
    for (int n = 0; n < 4; ++n) b[n] = *(const f16x8*)(Bs + rb[n]);
    #pragma unroll
    for (int m = 0; m < 4; ++m)
      #pragma unroll
      for (int n = 0; n < 4; ++n)
        acc[m][n] = __builtin_amdgcn_mfma_f32_16x16x32_f16(a[m], b[n], acc[m][n], 0, 0, 0);
    __syncthreads();
  }
  #pragma unroll
  for (int n = 0; n < 4; ++n) {
    const int gn = n0 + wc * 64 + n * 16 + (lane & 15);
    const float bov = bo[gn];
    #pragma unroll
    for (int m = 0; m < 4; ++m) {
      const int rbase = r0 + wr * 64 + m * 16 + ((lane >> 4) << 2);
      #pragma unroll
      for (int r = 0; r < 4; ++r)
        out[(size_t)(rbase + r) * 1024 + gn] = acc[m][n][r] + bov;
    }
  }
}

// ---------------------------------------------------------------------------
extern "C" void kernel_launch(void* const* d_in, const int* in_sizes, int n_in,
                              void* d_out, int out_size, void* d_ws, size_t ws_size,
                              hipStream_t stream)
{
  const float* states = (const float*)d_in[0];
  const float* mask   = (const float*)d_in[1];
  const float* hs     = (const float*)d_in[2];
  const float* Wa     = (const float*)d_in[3];
  const float* Wv     = (const float*)d_in[4];
  const float* bv     = (const float*)d_in[5];
  const float* Wg     = (const float*)d_in[6];
  const float* bg     = (const float*)d_in[7];
  const float* Wo     = (const float*)d_in[8];
  const float* bo     = (const float*)d_in[9];
  float* out = (float*)d_out;

  // workspace layout (bytes): total 21,497,984 (~20.5 MB). og aliases st16:
  // st16 is consumed by k_gemm_v before k_attn writes og (stream-ordered).
  char* ws = (char*)d_ws;
  f16*   st16    = (f16*)(ws);                   //  8 MB  states fp16 [4096][1024]
  f16*   og      = (f16*)(ws);                   //  8 MB  gated O fp16 (alias)
  f16*   Wv16    = (f16*)(ws + 8388608);         //  2 MB
  f16*   Wo16    = (f16*)(ws + 10485760);        //  2 MB
  float* sbuf    = (float*)(ws + 12582912);      // 256 KB s [32][2048]
  float* gsig    = (float*)(ws + 12845056);      // 256 KB sigmoid(g) [4096][16]
  f16*   vt      = (f16*)(ws + 13107200);        //  8 MB  V^T [2048][2048]
  float* partial = (float*)(ws + 21495808);      //  2 KB  mask absmax partials (512)
  float* Lbuf    = (float*)(ws + 21497856);      // 128 B  logit upper bounds

  k_prep<<<3072, 256, 0, stream>>>(states, mask, Wa, Wv, Wg, Wo, bg,
                                   st16, Wv16, Wo16, sbuf, gsig, partial);
  k_lmax<<<32, 64, 0, stream>>>(sbuf, partial, hs, Lbuf);
  k_gemm_v<<<dim3(8, 32), 256, 0, stream>>>(st16, Wv16, bv, vt);
  k_attn<<<dim3(16, 32, 2), 256, 0, stream>>>(mask, sbuf, gsig, hs, Lbuf, vt, og);
  k_gemm_out<<<dim3(8, 32), 256, 0, stream>>>(og, Wo16, bo, out);
}